// Round 1
// baseline (142.758 us; speedup 1.0000x reference)
//
#include <hip/hip_runtime.h>

constexpr int Hh = 320, Ww = 320, Cc = 32, Bb = 4, Nn = 20000;
constexpr int HWp = Hh * Ww;

// grid[src][b][y*W+x] = point index (src 0 = li coords, 1 = ra coords), -1 = empty
__global__ __launch_bounds__(256) void build_grid_k(
    const int* __restrict__ li_coors, const int* __restrict__ ra_coors,
    int* __restrict__ grids) {
  int idx = blockIdx.x * 256 + threadIdx.x;
  if (idx >= 2 * Bb * Nn) return;
  int src = idx / (Bb * Nn);
  int r = idx - src * (Bb * Nn);
  int b = r / Nn, n = r - b * Nn;
  const int* c = (src == 0 ? li_coors : ra_coors) + ((size_t)b * Nn + n) * 2;
  grids[((size_t)src * Bb + b) * HWp + c[0] * Ww + c[1]] = n;
}

// posv[dir][l][c] = pos[l] @ wv_dir.T  (wv = rows 64..95 of in_w)
__global__ __launch_bounds__(256) void posv_k(
    const float* __restrict__ pos, const float* __restrict__ in_w1,
    const float* __restrict__ in_w2, float* __restrict__ posv) {
  int t = blockIdx.x * 256 + threadIdx.x;
  if (t >= 2 * 9 * Cc) return;
  int dir = t / (9 * Cc);
  int rem = t - dir * 9 * Cc;
  int l = rem / Cc, ch = rem - l * Cc;
  const float* w = (dir == 0 ? in_w1 : in_w2) + (2 * Cc + ch) * Cc;
  const float* pl = pos + l * Cc;
  float acc = 0.f;
  for (int j = 0; j < Cc; j++) acc += pl[j] * w[j];
  posv[t] = acc;
}

// Per source set (li/ra) and batch: Qh (own-direction q proj, +bias),
// Kp/Vp (other-direction k/v proj, NO bias — bias handled analytically).
__global__ __launch_bounds__(256) void project_k(
    const float* __restrict__ li_feats, const float* __restrict__ ra_feats,
    const float* __restrict__ in_w1, const float* __restrict__ in_b1,
    const float* __restrict__ in_w2, const float* __restrict__ in_b2,
    float* __restrict__ Qh, float* __restrict__ Kp, float* __restrict__ Vp) {
  int sb = blockIdx.y;
  int src = sb >> 2, b = sb & 3;
  __shared__ __align__(16) float wq[Cc * Cc], wk[Cc * Cc], wv[Cc * Cc];
  __shared__ float bq[Cc];
  const float* wA = src == 0 ? in_w1 : in_w2;  // q weights: own direction
  const float* bA = src == 0 ? in_b1 : in_b2;
  const float* wB = src == 0 ? in_w2 : in_w1;  // k/v weights: other direction
  int t = threadIdx.x;
  for (int i = t; i < Cc * Cc; i += 256) {
    wq[i] = wA[i];
    wk[i] = wB[Cc * Cc + i];
    wv[i] = wB[2 * Cc * Cc + i];
  }
  if (t < Cc) bq[t] = bA[t];
  __syncthreads();
  int n = blockIdx.x * 256 + t;
  if (n >= Nn) return;
  const float* f = (src == 0 ? li_feats : ra_feats) + ((size_t)b * Nn + n) * Cc;
  float4 fr[8];
#pragma unroll
  for (int j = 0; j < 8; j++) fr[j] = ((const float4*)f)[j];
  int dirq = src, dirkv = 1 - src;
  float* qo = Qh + (((size_t)dirq * Bb + b) * Nn + n) * Cc;
  float* ko = Kp + (((size_t)dirkv * Bb + b) * Nn + n) * Cc;
  float* vo = Vp + (((size_t)dirkv * Bb + b) * Nn + n) * Cc;
  const float4* wq4 = (const float4*)wq;
  const float4* wk4 = (const float4*)wk;
  const float4* wv4 = (const float4*)wv;
#pragma unroll
  for (int c0 = 0; c0 < Cc; c0 += 4) {
    float aq[4], ak[4], av[4];
#pragma unroll
    for (int u = 0; u < 4; u++) { aq[u] = bq[c0 + u]; ak[u] = 0.f; av[u] = 0.f; }
#pragma unroll
    for (int j4 = 0; j4 < 8; j4++) {
      float4 f4 = fr[j4];
#pragma unroll
      for (int u = 0; u < 4; u++) {
        float4 q4 = wq4[(c0 + u) * 8 + j4];
        float4 k4 = wk4[(c0 + u) * 8 + j4];
        float4 v4 = wv4[(c0 + u) * 8 + j4];
        aq[u] += f4.x * q4.x + f4.y * q4.y + f4.z * q4.z + f4.w * q4.w;
        ak[u] += f4.x * k4.x + f4.y * k4.y + f4.z * k4.z + f4.w * k4.w;
        av[u] += f4.x * v4.x + f4.y * v4.y + f4.z * v4.z + f4.w * v4.w;
      }
    }
    *(float4*)(qo + c0) = make_float4(aq[0], aq[1], aq[2], aq[3]);
    *(float4*)(ko + c0) = make_float4(ak[0], ak[1], ak[2], ak[3]);
    *(float4*)(vo + c0) = make_float4(av[0], av[1], av[2], av[3]);
  }
}

// Per query point: 9-slot attention (2 heads of 16) + output projection.
__global__ __launch_bounds__(256) void attn_k(
    const int* __restrict__ li_coors, const int* __restrict__ ra_coors,
    const int* __restrict__ grids, const float* __restrict__ Qh,
    const float* __restrict__ Kp, const float* __restrict__ Vp,
    const float* __restrict__ posv, const float* __restrict__ in_b1,
    const float* __restrict__ in_b2, const float* __restrict__ out_w1,
    const float* __restrict__ out_b1, const float* __restrict__ out_w2,
    const float* __restrict__ out_b2, float* __restrict__ out_pts) {
  int db = blockIdx.y;
  int dir = db >> 2, b = db & 3;
  __shared__ __align__(16) float ow[Cc * Cc];
  __shared__ __align__(16) float pv[9 * Cc];
  __shared__ float obias[Cc], bk[Cc], bv[Cc];
  const float* owp = dir == 0 ? out_w1 : out_w2;
  const float* obp = dir == 0 ? out_b1 : out_b2;
  const float* ibp = dir == 0 ? in_b1 : in_b2;
  int t = threadIdx.x;
  for (int i = t; i < Cc * Cc; i += 256) ow[i] = owp[i];
  for (int i = t; i < 9 * Cc; i += 256) pv[i] = posv[dir * 9 * Cc + i];
  if (t < Cc) { obias[t] = obp[t]; bk[t] = ibp[Cc + t]; bv[t] = ibp[2 * Cc + t]; }
  __syncthreads();
  int n = blockIdx.x * 256 + t;
  if (n >= Nn) return;
  const int* qc = (dir == 0 ? li_coors : ra_coors) + ((size_t)b * Nn + n) * 2;
  int y = qc[0], x = qc[1];
  // kv grid: dir0 attends over ra (src1), dir1 over li (src0)
  const int* g = grids + ((size_t)(1 - dir) * Bb + b) * HWp;
  float4 qh4[8];
  const float4* qp = (const float4*)(Qh + (((size_t)dir * Bb + b) * Nn + n) * Cc);
#pragma unroll
  for (int j = 0; j < 8; j++) qh4[j] = qp[j];
  // invalid-slot score: qh . bk / 4 per head (reference keeps zero-K slots in softmax)
  float sinv0 = 0.f, sinv1 = 0.f;
  const float4* bk4 = (const float4*)bk;
#pragma unroll
  for (int j4 = 0; j4 < 4; j4++) {
    float4 b4 = bk4[j4], q4 = qh4[j4];
    sinv0 += q4.x * b4.x + q4.y * b4.y + q4.z * b4.z + q4.w * b4.w;
  }
#pragma unroll
  for (int j4 = 4; j4 < 8; j4++) {
    float4 b4 = bk4[j4], q4 = qh4[j4];
    sinv1 += q4.x * b4.x + q4.y * b4.y + q4.z * b4.z + q4.w * b4.w;
  }
  sinv0 *= 0.25f;
  sinv1 *= 0.25f;
  const int DY[9] = {0, -1, 1, 0, -1, 1, 0, -1, 1};
  const int DX[9] = {0, 0, 0, 1, 1, 1, -1, -1, -1};
  int sel[9];
  float s0[9], s1[9];
  const float* Kpb = Kp + ((size_t)dir * Bb + b) * Nn * Cc;
#pragma unroll
  for (int l = 0; l < 9; l++) {
    int cy = y + DY[l], cx = x + DX[l];
    int se = -1;
    if ((unsigned)cy < (unsigned)Hh && (unsigned)cx < (unsigned)Ww) se = g[cy * Ww + cx];
    sel[l] = se;
    float d0 = 0.f, d1 = 0.f;
    if (se >= 0) {
      const float4* kp = (const float4*)(Kpb + (size_t)se * Cc);
#pragma unroll
      for (int j4 = 0; j4 < 4; j4++) {
        float4 k4 = kp[j4], q4 = qh4[j4];
        d0 += q4.x * k4.x + q4.y * k4.y + q4.z * k4.z + q4.w * k4.w;
      }
#pragma unroll
      for (int j4 = 4; j4 < 8; j4++) {
        float4 k4 = kp[j4], q4 = qh4[j4];
        d1 += q4.x * k4.x + q4.y * k4.y + q4.z * k4.z + q4.w * k4.w;
      }
    }
    s0[l] = sinv0 + 0.25f * d0;
    s1[l] = sinv1 + 0.25f * d1;
  }
  float m0 = s0[0], m1 = s1[0];
#pragma unroll
  for (int l = 1; l < 9; l++) { m0 = fmaxf(m0, s0[l]); m1 = fmaxf(m1, s1[l]); }
  float sum0 = 0.f, sum1 = 0.f;
#pragma unroll
  for (int l = 0; l < 9; l++) {
    s0[l] = __expf(s0[l] - m0);
    s1[l] = __expf(s1[l] - m1);
    sum0 += s0[l];
    sum1 += s1[l];
  }
  float o[Cc];
#pragma unroll
  for (int j = 0; j < Cc; j++) o[j] = 0.f;
  const float* Vpb = Vp + ((size_t)dir * Bb + b) * Nn * Cc;
  const float4* pv4 = (const float4*)pv;
#pragma unroll
  for (int l = 0; l < 9; l++) {
    int se = sel[l];
    if (se >= 0) {
      const float4* vp = (const float4*)(Vpb + (size_t)se * Cc);
      float w0 = s0[l], w1 = s1[l];
#pragma unroll
      for (int j4 = 0; j4 < 8; j4++) {
        float4 v4 = vp[j4];
        float4 p4 = pv4[l * 8 + j4];
        float w = (j4 < 4) ? w0 : w1;
        o[j4 * 4 + 0] += w * (v4.x + p4.x);
        o[j4 * 4 + 1] += w * (v4.y + p4.y);
        o[j4 * 4 + 2] += w * (v4.z + p4.z);
        o[j4 * 4 + 3] += w * (v4.w + p4.w);
      }
    }
  }
  float r0 = 1.f / sum0, r1 = 1.f / sum1;
#pragma unroll
  for (int j = 0; j < 16; j++) o[j] = o[j] * r0 + bv[j];
#pragma unroll
  for (int j = 16; j < Cc; j++) o[j] = o[j] * r1 + bv[j];
  float* op = out_pts + (((size_t)dir * Bb + b) * Nn + n) * Cc;
  const float4* ow4 = (const float4*)ow;
#pragma unroll
  for (int c0 = 0; c0 < Cc; c0 += 4) {
    float a[4];
#pragma unroll
    for (int u = 0; u < 4; u++) {
      float acc = obias[c0 + u];
#pragma unroll
      for (int j4 = 0; j4 < 8; j4++) {
        float4 w4 = ow4[(c0 + u) * 8 + j4];
        acc += o[j4 * 4 + 0] * w4.x + o[j4 * 4 + 1] * w4.y + o[j4 * 4 + 2] * w4.z +
               o[j4 * 4 + 3] * w4.w;
      }
      a[u] = acc;
    }
    *(float4*)(op + c0) = make_float4(a[0], a[1], a[2], a[3]);
  }
}

// Inverted scatter: one thread per canvas pixel; channel stores are wave-coalesced.
__global__ __launch_bounds__(256) void scatter_k(
    const int* __restrict__ grids, const float* __restrict__ out_pts,
    float* __restrict__ out) {
  int db = blockIdx.y;
  int dir = db >> 2, b = db & 3;
  int p = blockIdx.x * 256 + threadIdx.x;
  // q-side grid: dir0 scatters at li coords (src0), dir1 at ra coords (src1)
  const int* g = grids + ((size_t)dir * Bb + b) * HWp;
  int se = g[p];
  float* ob = out + (((size_t)dir * Bb + b) * Cc) * HWp + p;
  if (se < 0) {
#pragma unroll
    for (int c = 0; c < Cc; c++) ob[(size_t)c * HWp] = 0.f;
  } else {
    const float4* sp = (const float4*)(out_pts + (((size_t)dir * Bb + b) * Nn + se) * Cc);
#pragma unroll
    for (int c4 = 0; c4 < 8; c4++) {
      float4 v = sp[c4];
      ob[(size_t)(c4 * 4 + 0) * HWp] = v.x;
      ob[(size_t)(c4 * 4 + 1) * HWp] = v.y;
      ob[(size_t)(c4 * 4 + 2) * HWp] = v.z;
      ob[(size_t)(c4 * 4 + 3) * HWp] = v.w;
    }
  }
}

extern "C" void kernel_launch(void* const* d_in, const int* in_sizes, int n_in,
                              void* d_out, int out_size, void* d_ws, size_t ws_size,
                              hipStream_t stream) {
  const float* li_feats = (const float*)d_in[0];
  const int* li_coors = (const int*)d_in[1];
  const float* ra_feats = (const float*)d_in[2];
  const int* ra_coors = (const int*)d_in[3];
  const float* pos = (const float*)d_in[4];
  const float* in_w1 = (const float*)d_in[5];
  const float* in_b1 = (const float*)d_in[6];
  const float* out_w1 = (const float*)d_in[7];
  const float* out_b1 = (const float*)d_in[8];
  const float* in_w2 = (const float*)d_in[9];
  const float* in_b2 = (const float*)d_in[10];
  const float* out_w2 = (const float*)d_in[11];
  const float* out_b2 = (const float*)d_in[12];

  char* ws = (char*)d_ws;
  size_t off = 0;
  int* grids = (int*)(ws + off);
  off += (size_t)2 * Bb * HWp * 4;  // 3,276,800 B
  float* Qh = (float*)(ws + off);
  off += (size_t)2 * Bb * Nn * Cc * 4;  // 20,480,000 B
  float* Kp = (float*)(ws + off);
  off += (size_t)2 * Bb * Nn * Cc * 4;
  float* Vp = (float*)(ws + off);
  off += (size_t)2 * Bb * Nn * Cc * 4;
  float* out_pts = (float*)(ws + off);
  off += (size_t)2 * Bb * Nn * Cc * 4;
  float* posv = (float*)(ws + off);
  off += (size_t)2 * 9 * Cc * 4;  // total ~85.2 MB

  hipMemsetAsync(grids, 0xFF, (size_t)2 * Bb * HWp * 4, stream);
  build_grid_k<<<(2 * Bb * Nn + 255) / 256, 256, 0, stream>>>(li_coors, ra_coors, grids);
  posv_k<<<3, 256, 0, stream>>>(pos, in_w1, in_w2, posv);
  dim3 gp((Nn + 255) / 256, 2 * Bb);
  project_k<<<gp, 256, 0, stream>>>(li_feats, ra_feats, in_w1, in_b1, in_w2, in_b2,
                                    Qh, Kp, Vp);
  attn_k<<<gp, 256, 0, stream>>>(li_coors, ra_coors, grids, Qh, Kp, Vp, posv, in_b1,
                                 in_b2, out_w1, out_b1, out_w2, out_b2, out_pts);
  dim3 gs(HWp / 256, 2 * Bb);
  scatter_k<<<gs, 256, 0, stream>>>(grids, out_pts, (float*)d_out);
}